// Round 6
// baseline (190.395 us; speedup 1.0000x reference)
//
#include <hip/hip_runtime.h>

#define WW 512
#define HH 256
#define TS 48
#define NB 2
#define TCH 12               // t-steps per block
#define NCH (TS / TCH)       // 4 chunks
#define KAPPA 0.01f
#define NU 0.01f

#define ROW(zz) (min(max((zz), 0), HH - 1) * WW)
#define LD2(p) (*reinterpret_cast<const float2*>(p))

__device__ __forceinline__ float2 f2add(const float2 a, const float2 b) {
    return make_float2(a.x + b.x, a.y + b.y);
}

// jnp.gradient first+second (gradient-of-gradient) along one axis, index i of n.
__device__ __forceinline__ void grad12(float fm2, float fm1, float fc, float fp1, float fp2,
                                       int i, int n, float invh, float& g, float& gg) {
    const float half = 0.5f * invh;
    if (i == 0) {
        g = (fp1 - fc) * invh;
        float g1 = (fp2 - fc) * half;
        gg = (g1 - g) * invh;
    } else if (i == n - 1) {
        g = (fc - fm1) * invh;
        float gm = (fc - fm2) * half;
        gg = (g - gm) * invh;
    } else {
        g = (fp1 - fm1) * half;
        float gim = (i == 1)     ? (fc - fm1) * invh : (fc - fm2) * half;
        float gip = (i == n - 2) ? (fp1 - fc) * invh : (fp2 - fc) * half;
        gg = (gip - gim) * half;
    }
}

__device__ __forceinline__ float grad1(float fm1, float fc, float fp1, int i, int n, float invh) {
    if (i == 0)     return (fp1 - fc) * invh;
    if (i == n - 1) return (fc - fm1) * invh;
    return (fp1 - fm1) * (0.5f * invh);
}

__global__ __launch_bounds__(256) void rbc_loss_kernel(const float* __restrict__ pred,
                                                       double* __restrict__ dacc) {
    const int sT = HH * WW;          // 131072
    const int sC = TS * sT;
    const int sB = 5 * sC;

    // XCD-chunked swizzle: 2048 blocks, 256 per XCD -> one XCD sweeps all z of
    // one (b, tc): z-neighbor row sharing stays inside its L2.
    const int bi = blockIdx.x;
    const int n  = (bi & 7) * (gridDim.x >> 3) + (bi >> 3);

    const int z  = n & (HH - 1);          // logical n = ((b*NCH + tc)*HH + z)
    const int tc = (n >> 8) & (NCH - 1);
    const int b  = n >> 10;
    const int t0 = tc * TCH;
    const int tEnd = t0 + TCH;

    const int lane = threadIdx.x & 63, w = threadIdx.x >> 6;
    const int x0 = threadIdx.x << 1;      // pair base, 0..510

    const float invdt = TS / 10.0f;
    const float invdx = (float)(WW / 6.283185307179586);
    const float invdz = HH / 2.0f;

    const float* __restrict__ pT = pred + (size_t)b * sB + 0 * (size_t)sC;
    const float* __restrict__ pU = pred + (size_t)b * sB + 1 * (size_t)sC;
    const float* __restrict__ pV = pred + (size_t)b * sB + 2 * (size_t)sC;
    const float* __restrict__ q3 = pred + (size_t)b * sB + 3 * (size_t)sC;
    const float* __restrict__ q4 = pred + (size_t)b * sB + 4 * (size_t)sC;

    const int rC   = z * WW + x0;
    const int rzm2 = ROW(z - 2) + x0, rzm1 = ROW(z - 1) + x0;
    const int rzp1 = ROW(z + 1) + x0, rzp2 = ROW(z + 2) + x0;

    const bool needL = (lane == 0)  && (x0 != 0);    // wave seam, not grid edge
    const bool needR = (lane == 63) && (x0 != 510);
    const int rSm  = z * WW + (needL ? x0 - 2 : x0 + 2);
    const int rSmP = z * WW + (needL ? x0 - 1 : x0 + 2);

    // ---- t-ring (centers t-1, t, t+1) + in-flight center (t+2) ----
    const int tp0 = max(t0 - 1, 0);
    float2 TcP = LD2(pT + (size_t)tp0 * sT + rC);
    float2 UcP = LD2(pU + (size_t)tp0 * sT + rC);
    float2 VcP = LD2(pV + (size_t)tp0 * sT + rC);
    float2 TcC = LD2(pT + (size_t)t0 * sT + rC);
    float2 UcC = LD2(pU + (size_t)t0 * sT + rC);
    float2 VcC = LD2(pV + (size_t)t0 * sT + rC);
    const int t1 = min(t0 + 1, TS - 1);
    float2 TcN = LD2(pT + (size_t)t1 * sT + rC);
    float2 UcN = LD2(pU + (size_t)t1 * sT + rC);
    float2 VcN = LD2(pV + (size_t)t1 * sT + rC);
    float2 CfT, CfU, CfV;

    // ---- double-buffered per-t load sets (A/B) ----
    float2 Tm2A, Tm1A, Tp1A, Tp2A, Um2A, Um1A, Up1A, Up2A, Vm2A, Vm1A, Vp1A, Vp2A;
    float2 A3mA, A3cA, A3pA, A4mA, A4cA, A4pA;
    float2 TseA, UseA, VseA; float P3sA, P4sA;
    float2 Tm2B, Tm1B, Tp1B, Tp2B, Um2B, Um1B, Up1B, Up2B, Vm2B, Vm1B, Vp1B, Vp2B;
    float2 A3mB, A3cB, A3pB, A4mB, A4cB, A4pB;
    float2 TseB, UseB, VseB; float P3sB, P4sB;

#define PF(S, tq) do {                                                            \
    const size_t _o = (size_t)(tq) * sT;                                          \
    Tm2##S = LD2(pT + _o + rzm2); Tm1##S = LD2(pT + _o + rzm1);                   \
    Tp1##S = LD2(pT + _o + rzp1); Tp2##S = LD2(pT + _o + rzp2);                   \
    Um2##S = LD2(pU + _o + rzm2); Um1##S = LD2(pU + _o + rzm1);                   \
    Up1##S = LD2(pU + _o + rzp1); Up2##S = LD2(pU + _o + rzp2);                   \
    Vm2##S = LD2(pV + _o + rzm2); Vm1##S = LD2(pV + _o + rzm1);                   \
    Vp1##S = LD2(pV + _o + rzp1); Vp2##S = LD2(pV + _o + rzp2);                   \
    A3m##S = LD2(q3 + _o + rzm1); A3c##S = LD2(q3 + _o + rC); A3p##S = LD2(q3 + _o + rzp1); \
    A4m##S = LD2(q4 + _o + rzm1); A4c##S = LD2(q4 + _o + rC); A4p##S = LD2(q4 + _o + rzp1); \
    if (needL | needR) {                                                          \
        Tse##S = LD2(pT + _o + rSm); Use##S = LD2(pU + _o + rSm);                 \
        Vse##S = LD2(pV + _o + rSm);                                              \
        P3s##S = q3[_o + rSmP]; P4s##S = q4[_o + rSmP];                           \
    }                                                                             \
} while (0)

#define PFC(tq) do {                                                              \
    const size_t _oc = (size_t)(tq) * sT;                                         \
    CfT = LD2(pT + _oc + rC); CfU = LD2(pU + _oc + rC); CfV = LD2(pV + _oc + rC); \
} while (0)

#define COMPUTE(S, tcur) do {                                                     \
    float2 Pm1 = f2add(A3m##S, A4m##S);                                           \
    float2 Pc  = f2add(A3c##S, A4c##S);                                           \
    float2 Pp1 = f2add(A3p##S, A4p##S);                                           \
    float TLx = __shfl_up(TcC.x, 1),   TLy = __shfl_up(TcC.y, 1);                 \
    float TRx = __shfl_down(TcC.x, 1), TRy = __shfl_down(TcC.y, 1);               \
    float ULx = __shfl_up(UcC.x, 1),   ULy = __shfl_up(UcC.y, 1);                 \
    float URx = __shfl_down(UcC.x, 1), URy = __shfl_down(UcC.y, 1);               \
    float VLx = __shfl_up(VcC.x, 1),   VLy = __shfl_up(VcC.y, 1);                 \
    float VRx = __shfl_down(VcC.x, 1), VRy = __shfl_down(VcC.y, 1);               \
    float PLy = __shfl_up(Pc.y, 1),    PRx = __shfl_down(Pc.x, 1);                \
    if (needL) {                                                                  \
        TLx = Tse##S.x; TLy = Tse##S.y; ULx = Use##S.x; ULy = Use##S.y;           \
        VLx = Vse##S.x; VLy = Vse##S.y; PLy = P3s##S + P4s##S;                    \
    } else if (needR) {                                                           \
        TRx = Tse##S.x; TRy = Tse##S.y; URx = Use##S.x; URy = Use##S.y;           \
        VRx = Vse##S.x; VRy = Vse##S.y; PRx = P3s##S + P4s##S;                    \
    }                                                                             \
    _Pragma("unroll")                                                             \
    for (int e = 0; e < 2; ++e) {                                                 \
        const int i = x0 + e;                                                     \
        const float txm2 = e ? TLy : TLx, txm1 = e ? TcC.x : TLy;                 \
        const float txc  = e ? TcC.y : TcC.x;                                     \
        const float txp1 = e ? TRx : TcC.y, txp2 = e ? TRy : TRx;                 \
        const float uxm2 = e ? ULy : ULx, uxm1 = e ? UcC.x : ULy;                 \
        const float uxc  = e ? UcC.y : UcC.x;                                     \
        const float uxp1 = e ? URx : UcC.y, uxp2 = e ? URy : URx;                 \
        const float vxm2 = e ? VLy : VLx, vxm1 = e ? VcC.x : VLy;                 \
        const float vxc  = e ? VcC.y : VcC.x;                                     \
        const float vxp1 = e ? VRx : VcC.y, vxp2 = e ? VRy : VRx;                 \
        const float pxm1 = e ? Pc.x : PLy;                                        \
        const float pxc  = e ? Pc.y : Pc.x;                                       \
        const float pxp1 = e ? PRx : Pc.y;                                        \
        const float tzm2 = e ? Tm2##S.y : Tm2##S.x, tzm1 = e ? Tm1##S.y : Tm1##S.x; \
        const float tzp1 = e ? Tp1##S.y : Tp1##S.x, tzp2 = e ? Tp2##S.y : Tp2##S.x; \
        const float uzm2 = e ? Um2##S.y : Um2##S.x, uzm1 = e ? Um1##S.y : Um1##S.x; \
        const float uzp1 = e ? Up1##S.y : Up1##S.x, uzp2 = e ? Up2##S.y : Up2##S.x; \
        const float vzm2 = e ? Vm2##S.y : Vm2##S.x, vzm1 = e ? Vm1##S.y : Vm1##S.x; \
        const float vzp1 = e ? Vp1##S.y : Vp1##S.x, vzp2 = e ? Vp2##S.y : Vp2##S.x; \
        const float pzm1 = e ? Pm1.y : Pm1.x, pzp1 = e ? Pp1.y : Pp1.x;           \
        const float tpv = e ? TcP.y : TcP.x, tnv = e ? TcN.y : TcN.x;             \
        const float upv = e ? UcP.y : UcP.x, unv = e ? UcN.y : UcN.x;             \
        const float vpv = e ? VcP.y : VcP.x, vnv = e ? VcN.y : VcN.x;             \
        float dTdx, dTdxx, dTdz, dTdzz;                                           \
        grad12(txm2, txm1, txc, txp1, txp2, i, WW, invdx, dTdx, dTdxx);           \
        grad12(tzm2, tzm1, txc, tzp1, tzp2, z, HH, invdz, dTdz, dTdzz);           \
        float dUdx, dUdxx, dUdz, dUdzz;                                           \
        grad12(uxm2, uxm1, uxc, uxp1, uxp2, i, WW, invdx, dUdx, dUdxx);           \
        grad12(uzm2, uzm1, uxc, uzp1, uzp2, z, HH, invdz, dUdz, dUdzz);           \
        float dVdx, dVdxx, dVdz, dVdzz;                                           \
        grad12(vxm2, vxm1, vxc, vxp1, vxp2, i, WW, invdx, dVdx, dVdxx);           \
        grad12(vzm2, vzm1, vxc, vzp1, vzp2, z, HH, invdz, dVdz, dVdzz);           \
        float dPdx = grad1(pxm1, pxc, pxp1, i, WW, invdx);                        \
        float dPdz = grad1(pzm1, pxc, pzp1, z, HH, invdz);                        \
        float dTdt, dUdt, dVdt;                                                   \
        if ((tcur) == 0) {                                                        \
            dTdt = (tnv - txc) * invdt;                                           \
            dUdt = (unv - uxc) * invdt;                                           \
            dVdt = (vnv - vxc) * invdt;                                           \
        } else if ((tcur) == TS - 1) {                                            \
            dTdt = (txc - tpv) * invdt;                                           \
            dUdt = (uxc - upv) * invdt;                                           \
            dVdt = (vxc - vpv) * invdt;                                           \
        } else {                                                                  \
            dTdt = (tnv - tpv) * (0.5f * invdt);                                  \
            dUdt = (unv - upv) * (0.5f * invdt);                                  \
            dVdt = (vnv - vpv) * (0.5f * invdt);                                  \
        }                                                                         \
        float dv = dUdx + dVdz;                                                   \
        float te = dTdt + uxc * dTdx + vxc * dTdz - KAPPA * (dTdxx + dTdzz);      \
        float xm = dUdt + uxc * dUdx + vxc * dUdz + dPdx - NU * (dUdxx + dUdzz);  \
        float zm = dVdt + uxc * dVdx + vxc * dVdz + dPdz - NU * (dVdxx + dVdzz) - txc; \
        acc += dv * dv + te * te + xm * xm + zm * zm;                             \
    }                                                                             \
    TcP = TcC; TcC = TcN; TcN = CfT;                                              \
    UcP = UcC; UcC = UcN; UcN = CfU;                                              \
    VcP = VcC; VcC = VcN; VcN = CfV;                                              \
} while (0)

    float acc = 0.f;

    // prologue: fill both buffers + in-flight center
    PF(A, t0);
    PF(B, min(t0 + 1, TS - 1));
    PFC(min(t0 + 2, TS - 1));

    #pragma unroll 1
    for (int tt = t0; tt < tEnd; tt += 2) {
        COMPUTE(A, tt);                          // waits only on A's loads
        if (tt + 2 < tEnd) PF(A, tt + 2);        // refill A; lands during COMPUTE(B)
        PFC(min(tt + 3, TS - 1));                // center for COMPUTE(B)'s ring shift
        COMPUTE(B, tt + 1);
        if (tt + 3 < tEnd) PF(B, tt + 3);
        PFC(min(tt + 4, TS - 1));
    }

    // block reduction: wave shfl -> LDS -> one double atomic per block
    #pragma unroll
    for (int off = 32; off; off >>= 1) acc += __shfl_down(acc, off, 64);
    __shared__ float wsum[4];
    if (lane == 0) wsum[w] = acc;
    __syncthreads();
    if (threadIdx.x == 0) {
        atomicAdd(dacc, (double)(wsum[0] + wsum[1] + wsum[2] + wsum[3]));
    }
}

__global__ void rbc_finalize(const double* __restrict__ dacc, float* __restrict__ out) {
    const double N = (double)NB * TS * HH * WW;   // 12,582,912
    out[0] = (float)(dacc[0] / N);
}

extern "C" void kernel_launch(void* const* d_in, const int* in_sizes, int n_in,
                              void* d_out, int out_size, void* d_ws, size_t ws_size,
                              hipStream_t stream) {
    const float* pred = (const float*)d_in[0];
    double* dacc = (double*)d_ws;
    hipMemsetAsync(dacc, 0, sizeof(double), stream);

    const int nblocks = NB * NCH * HH;   // 2048 blocks x 256 threads
    rbc_loss_kernel<<<nblocks, 256, 0, stream>>>(pred, dacc);
    rbc_finalize<<<1, 1, 0, stream>>>(dacc, (float*)d_out);
}

// Round 7
// 87.674 us; speedup vs baseline: 2.1716x; 2.1716x over previous
//
#include <hip/hip_runtime.h>

#define WW 512
#define HH 256
#define TS 48
#define NB 2
#define TCH 12               // t-steps per block
#define NCH (TS / TCH)       // 4 chunks
#define KAPPA 0.01f
#define NU 0.01f

#define ROW(zz) (min(max((zz), 0), HH - 1) * WW)
#define LD4(p) (*reinterpret_cast<const float4*>(p))
#define LD2(p) (*reinterpret_cast<const float2*>(p))

__device__ __forceinline__ float elem(const float4 v, int e) {
    return e == 0 ? v.x : e == 1 ? v.y : e == 2 ? v.z : v.w;
}
__device__ __forceinline__ float4 f4add(const float4 a, const float4 b) {
    return make_float4(a.x + b.x, a.y + b.y, a.z + b.z, a.w + b.w);
}

// jnp.gradient first+second (gradient-of-gradient) along one axis, index i of n.
__device__ __forceinline__ void grad12(float fm2, float fm1, float fc, float fp1, float fp2,
                                       int i, int n, float invh, float& g, float& gg) {
    const float half = 0.5f * invh;
    if (i == 0) {
        g = (fp1 - fc) * invh;
        float g1 = (fp2 - fc) * half;
        gg = (g1 - g) * invh;
    } else if (i == n - 1) {
        g = (fc - fm1) * invh;
        float gm = (fc - fm2) * half;
        gg = (g - gm) * invh;
    } else {
        g = (fp1 - fm1) * half;
        float gim = (i == 1)     ? (fc - fm1) * invh : (fc - fm2) * half;
        float gip = (i == n - 2) ? (fp1 - fc) * invh : (fp2 - fc) * half;
        gg = (gip - gim) * half;
    }
}

__device__ __forceinline__ float grad1(float fm1, float fc, float fp1, int i, int n, float invh) {
    if (i == 0)     return (fp1 - fc) * invh;
    if (i == n - 1) return (fc - fm1) * invh;
    return (fp1 - fm1) * (0.5f * invh);
}

__global__ __launch_bounds__(256) void rbc_loss_kernel(const float* __restrict__ pred,
                                                       double* __restrict__ dacc) {
    const int sT = HH * WW;          // 131072
    const int sC = TS * sT;
    const int sB = 5 * sC;

    // XCD-chunked swizzle: 1024 blocks, 128 per XCD -> one XCD sweeps all z of
    // one (b, tc): z-neighbor row reuse stays inside its L2.
    const int bi = blockIdx.x;
    const int n  = (bi & 7) * (gridDim.x >> 3) + (bi >> 3);

    const int zp = n & 127;               // n = ((b*NCH + tc)*128 + zp)
    const int tc = (n >> 7) & (NCH - 1);
    const int b  = n >> 9;
    const int t0 = tc * TCH;

    const int lane = threadIdx.x & 63, w = threadIdx.x >> 6;
    const int z  = (zp << 1) + (w >> 1);          // waves 0,1 -> row A; 2,3 -> row B
    const int x0 = ((w & 1) << 8) + (lane << 2);  // quad base within row half

    const float invdt = TS / 10.0f;
    const float invdx = (float)(WW / 6.283185307179586);
    const float invdz = HH / 2.0f;

    const float* __restrict__ pT = pred + (size_t)b * sB + 0 * (size_t)sC;
    const float* __restrict__ pU = pred + (size_t)b * sB + 1 * (size_t)sC;
    const float* __restrict__ pV = pred + (size_t)b * sB + 2 * (size_t)sC;
    const float* __restrict__ q3 = pred + (size_t)b * sB + 3 * (size_t)sC;
    const float* __restrict__ q4 = pred + (size_t)b * sB + 4 * (size_t)sC;

    const int rowB = z * WW;
    const int rC   = rowB + x0;
    const int rzm2 = ROW(z - 2) + x0, rzm1 = ROW(z - 1) + x0;
    const int rzp1 = ROW(z + 1) + x0, rzp2 = ROW(z + 2) + x0;

    // seam between the two half-row waves (x=255|256 of each row)
    const bool isR = (lane == 63) && !(w & 1);   // quad 252-255, needs 256,257
    const bool isL = (lane == 0)  &&  (w & 1);   // quad 256-259, needs 254,255
    const int rSm  = rowB + (isR ? 256 : 254);   // float2 covers both needed x
    const int rSmP = rowB + (isR ? 256 : 255);

    // t-ring warm-up: centers at t0-1 (clamped; only backward/central use it) and t0
    const int tp0 = max(t0 - 1, 0);
    float4 Tp = LD4(pT + (size_t)tp0 * sT + rC);
    float4 Up = LD4(pU + (size_t)tp0 * sT + rC);
    float4 Vp = LD4(pV + (size_t)tp0 * sT + rC);
    float4 Tc = LD4(pT + (size_t)t0 * sT + rC);
    float4 Uc = LD4(pU + (size_t)t0 * sT + rC);
    float4 Vc = LD4(pV + (size_t)t0 * sT + rC);

    float acc = 0.f;

    #pragma unroll 1
    for (int t = t0; t < t0 + TCH; ++t) {
        const size_t o  = (size_t)t * sT;
        const size_t on = (size_t)min(t + 1, TS - 1) * sT;

        // ---- issue order = consumption order (oldest loads consumed first) ----
        // P rows (needed first: shuffles + P-grads)
        float4 A3m = LD4(q3 + o + rzm1), A4m = LD4(q4 + o + rzm1);
        float4 A3c = LD4(q3 + o + rC),   A4c = LD4(q4 + o + rC);
        float4 A3p = LD4(q3 + o + rzp1), A4p = LD4(q4 + o + rzp1);
        // z-stencil rows (needed mid: z-grads)
        float4 Tm2 = LD4(pT + o + rzm2), Tm1 = LD4(pT + o + rzm1);
        float4 Tp1 = LD4(pT + o + rzp1), Tp2 = LD4(pT + o + rzp2);
        float4 Um2 = LD4(pU + o + rzm2), Um1 = LD4(pU + o + rzm1);
        float4 Up1 = LD4(pU + o + rzp1), Up2 = LD4(pU + o + rzp2);
        float4 Vm2 = LD4(pV + o + rzm2), Vm1 = LD4(pV + o + rzm1);
        float4 Vp1 = LD4(pV + o + rzp1), Vp2 = LD4(pV + o + rzp2);
        // seam fixups (2 lanes/wave, exec-masked)
        float2 Tse = make_float2(0.f, 0.f), Use = Tse, Vse = Tse; float Pse = 0.f;
        if (isR | isL) {
            Tse = LD2(pT + o + rSm); Use = LD2(pU + o + rSm); Vse = LD2(pV + o + rSm);
            Pse = q3[o + rSmP] + q4[o + rSmP];
        }
        // t+1 centers last (first HBM touch, consumed only by dt / ring shift)
        float4 Tn = LD4(pT + on + rC);
        float4 Un = LD4(pU + on + rC);
        float4 Vn = LD4(pV + on + rC);

        float4 Pm1 = f4add(A3m, A4m), Pc = f4add(A3c, A4c), Pp1 = f4add(A3p, A4p);

        // x-neighbors via intra-wave shuffles of center quads (ring regs, no wait)
        float Tl2 = __shfl_up(Tc.z, 1),   Tl3 = __shfl_up(Tc.w, 1);
        float Tr0 = __shfl_down(Tc.x, 1), Tr1 = __shfl_down(Tc.y, 1);
        float Ul2 = __shfl_up(Uc.z, 1),   Ul3 = __shfl_up(Uc.w, 1);
        float Ur0 = __shfl_down(Uc.x, 1), Ur1 = __shfl_down(Uc.y, 1);
        float Vl2 = __shfl_up(Vc.z, 1),   Vl3 = __shfl_up(Vc.w, 1);
        float Vr0 = __shfl_down(Vc.x, 1), Vr1 = __shfl_down(Vc.y, 1);
        float Pl3 = __shfl_up(Pc.w, 1),   Pr0 = __shfl_down(Pc.x, 1);

        if (isR) { Tr0 = Tse.x; Tr1 = Tse.y; Ur0 = Use.x; Ur1 = Use.y;
                   Vr0 = Vse.x; Vr1 = Vse.y; Pr0 = Pse; }
        if (isL) { Tl2 = Tse.x; Tl3 = Tse.y; Ul2 = Use.x; Ul3 = Use.y;
                   Vl2 = Vse.x; Vl3 = Vse.y; Pl3 = Pse; }

        #pragma unroll
        for (int e = 0; e < 4; ++e) {
            const int i = x0 + e;
            const float txm2 = e == 0 ? Tl2 : e == 1 ? Tl3 : elem(Tc, e - 2);
            const float txm1 = e == 0 ? Tl3 : elem(Tc, e - 1);
            const float txc  = elem(Tc, e);
            const float txp1 = e == 3 ? Tr0 : elem(Tc, e + 1);
            const float txp2 = e == 2 ? Tr0 : e == 3 ? Tr1 : elem(Tc, e + 2);
            const float uxm2 = e == 0 ? Ul2 : e == 1 ? Ul3 : elem(Uc, e - 2);
            const float uxm1 = e == 0 ? Ul3 : elem(Uc, e - 1);
            const float uxc  = elem(Uc, e);
            const float uxp1 = e == 3 ? Ur0 : elem(Uc, e + 1);
            const float uxp2 = e == 2 ? Ur0 : e == 3 ? Ur1 : elem(Uc, e + 2);
            const float vxm2 = e == 0 ? Vl2 : e == 1 ? Vl3 : elem(Vc, e - 2);
            const float vxm1 = e == 0 ? Vl3 : elem(Vc, e - 1);
            const float vxc  = elem(Vc, e);
            const float vxp1 = e == 3 ? Vr0 : elem(Vc, e + 1);
            const float vxp2 = e == 2 ? Vr0 : e == 3 ? Vr1 : elem(Vc, e + 2);
            const float pxm1 = e == 0 ? Pl3 : elem(Pc, e - 1);
            const float pxc  = elem(Pc, e);
            const float pxp1 = e == 3 ? Pr0 : elem(Pc, e + 1);

            // x-grads first (no new memory waits), then P, then z, then dt
            float dTdx, dTdxx, dTdz, dTdzz;
            grad12(txm2, txm1, txc, txp1, txp2, i, WW, invdx, dTdx, dTdxx);
            float dUdx, dUdxx, dUdz, dUdzz;
            grad12(uxm2, uxm1, uxc, uxp1, uxp2, i, WW, invdx, dUdx, dUdxx);
            float dVdx, dVdxx, dVdz, dVdzz;
            grad12(vxm2, vxm1, vxc, vxp1, vxp2, i, WW, invdx, dVdx, dVdxx);

            float dPdx = grad1(pxm1, pxc, pxp1, i, WW, invdx);
            float dPdz = grad1(elem(Pm1, e), pxc, elem(Pp1, e), z, HH, invdz);

            grad12(elem(Tm2, e), elem(Tm1, e), txc, elem(Tp1, e), elem(Tp2, e), z, HH, invdz, dTdz, dTdzz);
            grad12(elem(Um2, e), elem(Um1, e), uxc, elem(Up1, e), elem(Up2, e), z, HH, invdz, dUdz, dUdzz);
            grad12(elem(Vm2, e), elem(Vm1, e), vxc, elem(Vp1, e), elem(Vp2, e), z, HH, invdz, dVdz, dVdzz);

            float dTdt, dUdt, dVdt;   // t is loop-uniform
            if (t == 0) {
                dTdt = (elem(Tn, e) - txc) * invdt;
                dUdt = (elem(Un, e) - uxc) * invdt;
                dVdt = (elem(Vn, e) - vxc) * invdt;
            } else if (t == TS - 1) {
                dTdt = (txc - elem(Tp, e)) * invdt;
                dUdt = (uxc - elem(Up, e)) * invdt;
                dVdt = (vxc - elem(Vp, e)) * invdt;
            } else {
                dTdt = (elem(Tn, e) - elem(Tp, e)) * (0.5f * invdt);
                dUdt = (elem(Un, e) - elem(Up, e)) * (0.5f * invdt);
                dVdt = (elem(Vn, e) - elem(Vp, e)) * (0.5f * invdt);
            }

            float dv = dUdx + dVdz;
            float te = dTdt + uxc * dTdx + vxc * dTdz - KAPPA * (dTdxx + dTdzz);
            float xm = dUdt + uxc * dUdx + vxc * dUdz + dPdx - NU * (dUdxx + dUdzz);
            float zm = dVdt + uxc * dVdx + vxc * dVdz + dPdz - NU * (dVdxx + dVdzz) - txc;

            acc += dv * dv + te * te + xm * xm + zm * zm;
        }

        Tp = Tc; Tc = Tn;
        Up = Uc; Uc = Un;
        Vp = Vc; Vc = Vn;
    }

    // block reduction: wave shfl -> LDS -> one double atomic per block
    #pragma unroll
    for (int off = 32; off; off >>= 1) acc += __shfl_down(acc, off, 64);
    __shared__ float wsum[4];
    if (lane == 0) wsum[w] = acc;
    __syncthreads();
    if (threadIdx.x == 0) {
        atomicAdd(dacc, (double)(wsum[0] + wsum[1] + wsum[2] + wsum[3]));
    }
}

__global__ void rbc_finalize(const double* __restrict__ dacc, float* __restrict__ out) {
    const double N = (double)NB * TS * HH * WW;   // 12,582,912
    out[0] = (float)(dacc[0] / N);
}

extern "C" void kernel_launch(void* const* d_in, const int* in_sizes, int n_in,
                              void* d_out, int out_size, void* d_ws, size_t ws_size,
                              hipStream_t stream) {
    const float* pred = (const float*)d_in[0];
    double* dacc = (double*)d_ws;
    hipMemsetAsync(dacc, 0, sizeof(double), stream);

    const int nblocks = NB * NCH * (HH / 2);   // 1024 blocks x 256 threads
    rbc_loss_kernel<<<nblocks, 256, 0, stream>>>(pred, dacc);
    rbc_finalize<<<1, 1, 0, stream>>>(dacc, (float*)d_out);
}